// Round 2
// baseline (797.282 us; speedup 1.0000x reference)
//
#include <hip/hip_runtime.h>
#include <math.h>

#define CH 256

__device__ __forceinline__ float gelu_exact(float v) {
    return 0.5f * v * (1.0f + erff(v * 0.70710678118654752f));
}

// ---------------- GEMM: out[M x 256] = A[M x K] @ W[K x 256] + bias (+GELU) ----
// Tile 64x128, BK=16, 128 threads, 8x8 microtile (split-half rows/cols).
// B/FMA = 1.0 (vs 1.5 for 8x4) -> relieves LDS throughput bound.
template<bool DOGELU>
__global__ __launch_bounds__(128) void gemm_kernel(const float* __restrict__ A,
                                                   const float* __restrict__ W,
                                                   const float* __restrict__ bias,
                                                   float* __restrict__ out,
                                                   int M, int K)
{
    const int BM = 64, BN = 128, BK = 16;
    __shared__ float As[BK][BM + 4];   // [16][68]
    __shared__ float Bs[BK][BN + 4];   // [16][132]

    int tid = threadIdx.x;
    int m0 = blockIdx.x * BM;
    int n0 = blockIdx.y * BN;
    int ty = tid >> 4;        // 0..7  (row groups of 4, two halves)
    int tx = tid & 15;        // 0..15 (col groups of 4, two halves)

    float acc[8][8];
#pragma unroll
    for (int i = 0; i < 8; i++)
#pragma unroll
        for (int j = 0; j < 8; j++) acc[i][j] = 0.f;

    const int arow = tid >> 1;          // 0..63
    const int ak   = (tid & 1) * 8;     // 0 or 8
    const int brow = tid >> 3;          // 0..15 (k)
    const int bcol = (tid & 7) * 16;    // 0..112
    const bool kvec = ((K & 3) == 0);

    for (int k0 = 0; k0 < K; k0 += BK) {
        // ---- stage A tile (transposed into As[k][row]) ----
        {
            int gr = m0 + arow;
            bool rowok = gr < M;
            if (rowok && kvec && (k0 + BK <= K)) {
                const float* src = A + (size_t)gr * K + k0 + ak;
                float4 v0 = *(const float4*)(src);
                float4 v1 = *(const float4*)(src + 4);
                As[ak + 0][arow] = v0.x; As[ak + 1][arow] = v0.y;
                As[ak + 2][arow] = v0.z; As[ak + 3][arow] = v0.w;
                As[ak + 4][arow] = v1.x; As[ak + 5][arow] = v1.y;
                As[ak + 6][arow] = v1.z; As[ak + 7][arow] = v1.w;
            } else {
#pragma unroll
                for (int i = 0; i < 8; i++) {
                    int k = k0 + ak + i;
                    As[ak + i][arow] = (rowok && k < K) ? A[(size_t)gr * K + k] : 0.f;
                }
            }
        }
        // ---- stage B tile (4 x float4 per thread) ----
        {
            int gk = k0 + brow;
            if (gk < K) {
                const float* src = W + (size_t)gk * CH + n0 + bcol;
#pragma unroll
                for (int q = 0; q < 4; q++) {
                    float4 v = *(const float4*)(src + q * 4);
                    *(float4*)&Bs[brow][bcol + q * 4] = v;
                }
            } else {
#pragma unroll
                for (int q = 0; q < 4; q++)
                    *(float4*)&Bs[brow][bcol + q * 4] = float4{0.f, 0.f, 0.f, 0.f};
            }
        }
        __syncthreads();

#pragma unroll
        for (int kk = 0; kk < BK; kk++) {
            float a[8], b[8];
            *(float4*)&a[0] = *(const float4*)&As[kk][ty * 4];
            *(float4*)&a[4] = *(const float4*)&As[kk][32 + ty * 4];
            *(float4*)&b[0] = *(const float4*)&Bs[kk][tx * 4];
            *(float4*)&b[4] = *(const float4*)&Bs[kk][64 + tx * 4];
#pragma unroll
            for (int i = 0; i < 8; i++)
#pragma unroll
                for (int j = 0; j < 8; j++)
                    acc[i][j] = fmaf(a[i], b[j], acc[i][j]);
        }
        __syncthreads();
    }

    // ---- epilogue ----
    float bl[4], bh[4];
    *(float4*)&bl[0] = *(const float4*)(bias + n0 + tx * 4);
    *(float4*)&bh[0] = *(const float4*)(bias + n0 + 64 + tx * 4);
#pragma unroll
    for (int i = 0; i < 8; i++) {
        int row = m0 + ((i < 4) ? (ty * 4 + i) : (32 + ty * 4 + (i - 4)));
        if (row < M) {
            float ol[4], oh[4];
#pragma unroll
            for (int j = 0; j < 4; j++) {
                float v0 = acc[i][j] + bl[j];
                float v1 = acc[i][j + 4] + bh[j];
                ol[j] = DOGELU ? gelu_exact(v0) : v0;
                oh[j] = DOGELU ? gelu_exact(v1) : v1;
            }
            *(float4*)(out + (size_t)row * CH + n0 + tx * 4) = *(float4*)&ol[0];
            *(float4*)(out + (size_t)row * CH + n0 + 64 + tx * 4) = *(float4*)&oh[0];
        }
    }
}

// ---------------- CSR build ----------------
__global__ void zero_int_kernel(int* p, int n) {
    int i = blockIdx.x * blockDim.x + threadIdx.x;
    if (i < n) p[i] = 0;
}

__global__ void degree_kernel(const int* __restrict__ ei, int E, int* deg) {
    int e = blockIdx.x * blockDim.x + threadIdx.x;
    if (e < E) atomicAdd(&deg[ei[E + e]], 1);
}

// Hierarchical exclusive scan: 1024 elems/block (4/thread).
__global__ void scan_part_kernel(const int* __restrict__ deg, int* bsum, int N) {
    int t = threadIdx.x;
    int base = blockIdx.x * 1024 + t * 4;
    int4 v = {0, 0, 0, 0};
    if (base + 3 < N) v = *(const int4*)(deg + base);
    else {
        if (base + 0 < N) v.x = deg[base + 0];
        if (base + 1 < N) v.y = deg[base + 1];
        if (base + 2 < N) v.z = deg[base + 2];
        if (base + 3 < N) v.w = deg[base + 3];
    }
    __shared__ int sh[256];
    sh[t] = v.x + v.y + v.z + v.w;
    __syncthreads();
    for (int off = 128; off; off >>= 1) {
        if (t < off) sh[t] += sh[t + off];
        __syncthreads();
    }
    if (t == 0) bsum[blockIdx.x] = sh[0];
}

__global__ void scan_top_kernel(const int* __restrict__ bsum, int* boff, int B) {
    __shared__ int sh[256];
    int t = threadIdx.x;
    int own = (t < B) ? bsum[t] : 0;
    sh[t] = own;
    __syncthreads();
    for (int off = 1; off < 256; off <<= 1) {
        int v = (t >= off) ? sh[t - off] : 0;
        __syncthreads();
        sh[t] += v;
        __syncthreads();
    }
    if (t < B) boff[t] = sh[t] - own;   // exclusive
}

__global__ void scan_final_kernel(const int* __restrict__ deg, const int* __restrict__ boff,
                                  int* row_ptr, int* fill_pos, float* inv, int N, int E) {
    int t = threadIdx.x;
    int base = blockIdx.x * 1024 + t * 4;
    int4 v = {0, 0, 0, 0};
    if (base + 3 < N) v = *(const int4*)(deg + base);
    else {
        if (base + 0 < N) v.x = deg[base + 0];
        if (base + 1 < N) v.y = deg[base + 1];
        if (base + 2 < N) v.z = deg[base + 2];
        if (base + 3 < N) v.w = deg[base + 3];
    }
    int own = v.x + v.y + v.z + v.w;
    __shared__ int sh[256];
    sh[t] = own;
    __syncthreads();
    for (int off = 1; off < 256; off <<= 1) {
        int s = (t >= off) ? sh[t - off] : 0;
        __syncthreads();
        sh[t] += s;
        __syncthreads();
    }
    int run = boff[blockIdx.x] + (sh[t] - own);   // exclusive prefix for this thread
    int4 rp;
    rp.x = run;
    rp.y = run + v.x;
    rp.z = rp.y + v.y;
    rp.w = rp.z + v.z;
    if (base + 3 < N) {
        *(int4*)(row_ptr + base) = rp;
        *(int4*)(fill_pos + base) = rp;
        float4 iv;
        iv.x = 1.0f / fmaxf((float)v.x, 1.0f);
        iv.y = 1.0f / fmaxf((float)v.y, 1.0f);
        iv.z = 1.0f / fmaxf((float)v.z, 1.0f);
        iv.w = 1.0f / fmaxf((float)v.w, 1.0f);
        *(float4*)(inv + base) = iv;
    } else {
        int rr[4] = {rp.x, rp.y, rp.z, rp.w};
        int dd[4] = {v.x, v.y, v.z, v.w};
        for (int q = 0; q < 4; q++) {
            if (base + q < N) {
                row_ptr[base + q] = rr[q];
                fill_pos[base + q] = rr[q];
                inv[base + q] = 1.0f / fmaxf((float)dd[q], 1.0f);
            }
        }
    }
    if (blockIdx.x == 0 && t == 0) row_ptr[N] = E;
}

__global__ void fill_kernel(const int* __restrict__ ei, int E, int* fill_pos, int* colv) {
    int e = blockIdx.x * blockDim.x + threadIdx.x;
    if (e < E) {
        int p = atomicAdd(&fill_pos[ei[E + e]], 1);
        colv[p] = ei[e];
    }
}

// ---------------- aggregation + mean ----------------
__global__ void agg_kernel(const float* __restrict__ t, const int* __restrict__ row_ptr,
                           const int* __restrict__ colv, const float* __restrict__ inv,
                           float* __restrict__ agg, int N) {
    int n = blockIdx.x * 4 + (threadIdx.x >> 6);
    if (n >= N) return;
    int lane = threadIdx.x & 63;
    int s = row_ptr[n], e = row_ptr[n + 1];
    float a0 = 0.f, a1 = 0.f, a2 = 0.f, a3 = 0.f;
    for (int j = s; j < e; j++) {
        const float* p = t + (size_t)colv[j] * CH + lane * 4;
        float4 v = *(const float4*)p;
        a0 += v.x; a1 += v.y; a2 += v.z; a3 += v.w;
    }
    float sc = inv[n];
    float o[4] = {a0 * sc, a1 * sc, a2 * sc, a3 * sc};
    *(float4*)(agg + (size_t)n * CH + lane * 4) = *(float4*)&o[0];
}

__global__ void mean_kernel(const float* __restrict__ h, float* __restrict__ out, int N) {
    int n = blockIdx.x * 4 + (threadIdx.x >> 6);
    if (n >= N) return;
    int lane = threadIdx.x & 63;
    float4 v = *(const float4*)(h + (size_t)n * CH + lane * 4);
    float s = v.x + v.y + v.z + v.w;
#pragma unroll
    for (int off = 32; off; off >>= 1) s += __shfl_down(s, off, 64);
    if (lane == 0) out[n] = s * (1.0f / 256.0f);
}

extern "C" void kernel_launch(void* const* d_in, const int* in_sizes, int n_in,
                              void* d_out, int out_size, void* d_ws, size_t ws_size,
                              hipStream_t stream) {
    const float* x       = (const float*)d_in[0];
    const int*   ei      = (const int*)d_in[1];
    const float* W_embed = (const float*)d_in[2];
    const float* b_embed = (const float*)d_in[3];
    const float* W1      = (const float*)d_in[4];
    const float* b1      = (const float*)d_in[5];
    const float* W2      = (const float*)d_in[6];
    const float* b2      = (const float*)d_in[7];
    float* out = (float*)d_out;

    int N = in_sizes[0] / 118;
    int E = in_sizes[1] / 2;
    int SB = (N + 1023) / 1024;   // scan blocks

    // workspace layout
    float* h        = (float*)d_ws;                 // N*256
    float* t        = h + (size_t)N * CH;           // N*256
    float* agg      = t + (size_t)N * CH;           // N*256
    float* inv      = agg + (size_t)N * CH;         // N
    int*   deg      = (int*)(inv + N);              // N
    int*   row_ptr  = deg + N;                      // N+1
    int*   fill_pos = row_ptr + (N + 1);            // N
    int*   colv     = fill_pos + N;                 // E
    int*   bsum     = colv + E;                     // SB
    int*   boff     = bsum + 256;                   // SB

    // CSR build (per launch; deterministic)
    zero_int_kernel<<<(N + 255) / 256, 256, 0, stream>>>(deg, N);
    degree_kernel<<<(E + 255) / 256, 256, 0, stream>>>(ei, E, deg);
    scan_part_kernel<<<SB, 256, 0, stream>>>(deg, bsum, N);
    scan_top_kernel<<<1, 256, 0, stream>>>(bsum, boff, SB);
    scan_final_kernel<<<SB, 256, 0, stream>>>(deg, boff, row_ptr, fill_pos, inv, N, E);
    fill_kernel<<<(E + 255) / 256, 256, 0, stream>>>(ei, E, fill_pos, colv);

    dim3 gg((N + 63) / 64, 2);
    // embed: h = x @ W_embed + b_embed
    gemm_kernel<false><<<gg, 128, 0, stream>>>(x, W_embed, b_embed, h, N, 118);
    for (int l = 0; l < 4; l++) {
        gemm_kernel<true><<<gg, 128, 0, stream>>>(h, W1 + (size_t)l * CH * CH,
                                                  b1 + (size_t)l * CH, t, N, CH);
        agg_kernel<<<(N + 3) / 4, 256, 0, stream>>>(t, row_ptr, colv, inv, agg, N);
        gemm_kernel<true><<<gg, 128, 0, stream>>>(agg, W2 + (size_t)l * CH * CH,
                                                  b2 + (size_t)l * CH, h, N, CH);
    }
    mean_kernel<<<(N + 3) / 4, 256, 0, stream>>>(h, out, N);
}

// Round 3
// 697.680 us; speedup vs baseline: 1.1428x; 1.1428x over previous
//
#include <hip/hip_runtime.h>
#include <math.h>

#define CH 256

__device__ __forceinline__ float gelu_exact(float v) {
    return 0.5f * v * (1.0f + erff(v * 0.70710678118654752f));
}

// ---------------- GEMM: out[M x 256] = A[M x K] @ W[K x 256] + bias (+GELU) ----
// Tile 128x64, BK=64, 256 threads, 8x4 micro. Single-buffer LDS (51.2KB) ->
// up to 3 blocks/CU; grid 157x4=628 blocks -> ~10 waves/CU for latency hiding.
// Fragment reads: As = 16-way broadcast (conflict-free), Bs = 2-way (free).
template<bool DOGELU>
__global__ __launch_bounds__(256) void gemm_kernel(const float* __restrict__ A,
                                                   const float* __restrict__ W,
                                                   const float* __restrict__ bias,
                                                   float* __restrict__ out,
                                                   int M, int K)
{
    const int BM = 128, BN = 64, BK = 64;
    __shared__ float As[BK][BM + 4];   // [64][132]  33.8KB, k-major (transposed)
    __shared__ float Bs[BK][BN + 4];   // [64][68]   17.4KB

    int tid = threadIdx.x;
    int m0 = blockIdx.x * BM;
    int n0 = blockIdx.y * BN;
    int ty = tid >> 4;        // 0..15 -> 8 rows each
    int tx = tid & 15;        // 0..15 -> 4 cols each

    float acc[8][4];
#pragma unroll
    for (int i = 0; i < 8; i++)
#pragma unroll
        for (int j = 0; j < 4; j++) acc[i][j] = 0.f;

    // staging assignments
    const int s_arow = tid >> 2;        // 0..63 (+ it*64)
    const int s_akq  = tid & 3;         // k sub-block of 16
    const int s_bk   = tid >> 4;        // 0..15 (+ it*16)
    const int s_bc   = (tid & 15) * 4;  // col
    const bool kalign = ((K & 3) == 0);

    for (int k0 = 0; k0 < K; k0 += BK) {
        const bool fullk = kalign && (k0 + BK <= K);
        // ---- stage A tile (transpose into As[k][row]); row-clamped so always finite
#pragma unroll
        for (int it = 0; it < 2; it++) {
            int row = it * 64 + s_arow;
            int grow = min(m0 + row, M - 1);
            const float* src = A + (size_t)grow * K;
            if (fullk) {
                int kb = k0 + s_akq * 16;
                float4 v0 = *(const float4*)(src + kb);
                float4 v1 = *(const float4*)(src + kb + 4);
                float4 v2 = *(const float4*)(src + kb + 8);
                float4 v3 = *(const float4*)(src + kb + 12);
                int kr = s_akq * 16;
                As[kr +  0][row] = v0.x; As[kr +  1][row] = v0.y;
                As[kr +  2][row] = v0.z; As[kr +  3][row] = v0.w;
                As[kr +  4][row] = v1.x; As[kr +  5][row] = v1.y;
                As[kr +  6][row] = v1.z; As[kr +  7][row] = v1.w;
                As[kr +  8][row] = v2.x; As[kr +  9][row] = v2.y;
                As[kr + 10][row] = v2.z; As[kr + 11][row] = v2.w;
                As[kr + 12][row] = v3.x; As[kr + 13][row] = v3.y;
                As[kr + 14][row] = v3.z; As[kr + 15][row] = v3.w;
            } else {
#pragma unroll
                for (int q = 0; q < 16; q++) {
                    int k = k0 + s_akq * 16 + q;
                    As[s_akq * 16 + q][row] = (k < K) ? src[min(k, K - 1)] : 0.f;
                }
            }
        }
        // ---- stage B tile (zero-filled beyond K)
#pragma unroll
        for (int it = 0; it < 4; it++) {
            int kr = it * 16 + s_bk;
            int gk = k0 + kr;
            float4 v = {0.f, 0.f, 0.f, 0.f};
            if (gk < K) v = *(const float4*)(W + (size_t)gk * CH + n0 + s_bc);
            *(float4*)&Bs[kr][s_bc] = v;
        }
        __syncthreads();

#pragma unroll 16
        for (int kk = 0; kk < BK; kk++) {
            float a[8], b[4];
            *(float4*)&a[0] = *(const float4*)&As[kk][ty * 8];
            *(float4*)&a[4] = *(const float4*)&As[kk][ty * 8 + 4];
            *(float4*)&b[0] = *(const float4*)&Bs[kk][tx * 4];
#pragma unroll
            for (int i = 0; i < 8; i++)
#pragma unroll
                for (int j = 0; j < 4; j++)
                    acc[i][j] = fmaf(a[i], b[j], acc[i][j]);
        }
        __syncthreads();
    }

    // ---- epilogue: bias (+GELU), float4 stores ----
    float b4[4];
    *(float4*)&b4[0] = *(const float4*)(bias + n0 + tx * 4);
#pragma unroll
    for (int i = 0; i < 8; i++) {
        int row = m0 + ty * 8 + i;
        if (row < M) {
            float o[4];
#pragma unroll
            for (int j = 0; j < 4; j++) {
                float v = acc[i][j] + b4[j];
                o[j] = DOGELU ? gelu_exact(v) : v;
            }
            *(float4*)(out + (size_t)row * CH + n0 + tx * 4) = *(float4*)&o[0];
        }
    }
}

// ---------------- CSR build ----------------
__global__ void zero_int_kernel(int* p, int n) {
    int i = blockIdx.x * blockDim.x + threadIdx.x;
    if (i < n) p[i] = 0;
}

__global__ void degree_kernel(const int* __restrict__ ei, int E, int* deg) {
    int e = blockIdx.x * blockDim.x + threadIdx.x;
    if (e < E) atomicAdd(&deg[ei[E + e]], 1);
}

// Hierarchical exclusive scan: 1024 elems/block (4/thread).
__global__ void scan_part_kernel(const int* __restrict__ deg, int* bsum, int N) {
    int t = threadIdx.x;
    int base = blockIdx.x * 1024 + t * 4;
    int4 v = {0, 0, 0, 0};
    if (base + 3 < N) v = *(const int4*)(deg + base);
    else {
        if (base + 0 < N) v.x = deg[base + 0];
        if (base + 1 < N) v.y = deg[base + 1];
        if (base + 2 < N) v.z = deg[base + 2];
        if (base + 3 < N) v.w = deg[base + 3];
    }
    __shared__ int sh[256];
    sh[t] = v.x + v.y + v.z + v.w;
    __syncthreads();
    for (int off = 128; off; off >>= 1) {
        if (t < off) sh[t] += sh[t + off];
        __syncthreads();
    }
    if (t == 0) bsum[blockIdx.x] = sh[0];
}

__global__ void scan_top_kernel(const int* __restrict__ bsum, int* boff, int B) {
    __shared__ int sh[256];
    int t = threadIdx.x;
    int own = (t < B) ? bsum[t] : 0;
    sh[t] = own;
    __syncthreads();
    for (int off = 1; off < 256; off <<= 1) {
        int v = (t >= off) ? sh[t - off] : 0;
        __syncthreads();
        sh[t] += v;
        __syncthreads();
    }
    if (t < B) boff[t] = sh[t] - own;   // exclusive
}

__global__ void scan_final_kernel(const int* __restrict__ deg, const int* __restrict__ boff,
                                  int* row_ptr, int* fill_pos, float* inv, int N, int E) {
    int t = threadIdx.x;
    int base = blockIdx.x * 1024 + t * 4;
    int4 v = {0, 0, 0, 0};
    if (base + 3 < N) v = *(const int4*)(deg + base);
    else {
        if (base + 0 < N) v.x = deg[base + 0];
        if (base + 1 < N) v.y = deg[base + 1];
        if (base + 2 < N) v.z = deg[base + 2];
        if (base + 3 < N) v.w = deg[base + 3];
    }
    int own = v.x + v.y + v.z + v.w;
    __shared__ int sh[256];
    sh[t] = own;
    __syncthreads();
    for (int off = 1; off < 256; off <<= 1) {
        int s = (t >= off) ? sh[t - off] : 0;
        __syncthreads();
        sh[t] += s;
        __syncthreads();
    }
    int run = boff[blockIdx.x] + (sh[t] - own);   // exclusive prefix for this thread
    int4 rp;
    rp.x = run;
    rp.y = run + v.x;
    rp.z = rp.y + v.y;
    rp.w = rp.z + v.z;
    if (base + 3 < N) {
        *(int4*)(row_ptr + base) = rp;
        *(int4*)(fill_pos + base) = rp;
        float4 iv;
        iv.x = 1.0f / fmaxf((float)v.x, 1.0f);
        iv.y = 1.0f / fmaxf((float)v.y, 1.0f);
        iv.z = 1.0f / fmaxf((float)v.z, 1.0f);
        iv.w = 1.0f / fmaxf((float)v.w, 1.0f);
        *(float4*)(inv + base) = iv;
    } else {
        int rr[4] = {rp.x, rp.y, rp.z, rp.w};
        int dd[4] = {v.x, v.y, v.z, v.w};
        for (int q = 0; q < 4; q++) {
            if (base + q < N) {
                row_ptr[base + q] = rr[q];
                fill_pos[base + q] = rr[q];
                inv[base + q] = 1.0f / fmaxf((float)dd[q], 1.0f);
            }
        }
    }
    if (blockIdx.x == 0 && t == 0) row_ptr[N] = E;
}

__global__ void fill_kernel(const int* __restrict__ ei, int E, int* fill_pos, int* colv) {
    int e = blockIdx.x * blockDim.x + threadIdx.x;
    if (e < E) {
        int p = atomicAdd(&fill_pos[ei[E + e]], 1);
        colv[p] = ei[e];
    }
}

// ---------------- aggregation + mean ----------------
__global__ void agg_kernel(const float* __restrict__ t, const int* __restrict__ row_ptr,
                           const int* __restrict__ colv, const float* __restrict__ inv,
                           float* __restrict__ agg, int N) {
    int n = blockIdx.x * 4 + (threadIdx.x >> 6);
    if (n >= N) return;
    int lane = threadIdx.x & 63;
    int s = row_ptr[n], e = row_ptr[n + 1];
    float a0 = 0.f, a1 = 0.f, a2 = 0.f, a3 = 0.f;
    for (int j = s; j < e; j++) {
        const float* p = t + (size_t)colv[j] * CH + lane * 4;
        float4 v = *(const float4*)p;
        a0 += v.x; a1 += v.y; a2 += v.z; a3 += v.w;
    }
    float sc = inv[n];
    float o[4] = {a0 * sc, a1 * sc, a2 * sc, a3 * sc};
    *(float4*)(agg + (size_t)n * CH + lane * 4) = *(float4*)&o[0];
}

__global__ void mean_kernel(const float* __restrict__ h, float* __restrict__ out, int N) {
    int n = blockIdx.x * 4 + (threadIdx.x >> 6);
    if (n >= N) return;
    int lane = threadIdx.x & 63;
    float4 v = *(const float4*)(h + (size_t)n * CH + lane * 4);
    float s = v.x + v.y + v.z + v.w;
#pragma unroll
    for (int off = 32; off; off >>= 1) s += __shfl_down(s, off, 64);
    if (lane == 0) out[n] = s * (1.0f / 256.0f);
}

extern "C" void kernel_launch(void* const* d_in, const int* in_sizes, int n_in,
                              void* d_out, int out_size, void* d_ws, size_t ws_size,
                              hipStream_t stream) {
    const float* x       = (const float*)d_in[0];
    const int*   ei      = (const int*)d_in[1];
    const float* W_embed = (const float*)d_in[2];
    const float* b_embed = (const float*)d_in[3];
    const float* W1      = (const float*)d_in[4];
    const float* b1      = (const float*)d_in[5];
    const float* W2      = (const float*)d_in[6];
    const float* b2      = (const float*)d_in[7];
    float* out = (float*)d_out;

    int N = in_sizes[0] / 118;
    int E = in_sizes[1] / 2;
    int SB = (N + 1023) / 1024;   // scan blocks

    // workspace layout
    float* h        = (float*)d_ws;                 // N*256
    float* t        = h + (size_t)N * CH;           // N*256
    float* agg      = t + (size_t)N * CH;           // N*256
    float* inv      = agg + (size_t)N * CH;         // N
    int*   deg      = (int*)(inv + N);              // N
    int*   row_ptr  = deg + N;                      // N+1
    int*   fill_pos = row_ptr + (N + 1);            // N
    int*   colv     = fill_pos + N;                 // E
    int*   bsum     = colv + E;                     // SB
    int*   boff     = bsum + 256;                   // SB

    // CSR build (per launch; deterministic)
    zero_int_kernel<<<(N + 255) / 256, 256, 0, stream>>>(deg, N);
    degree_kernel<<<(E + 255) / 256, 256, 0, stream>>>(ei, E, deg);
    scan_part_kernel<<<SB, 256, 0, stream>>>(deg, bsum, N);
    scan_top_kernel<<<1, 256, 0, stream>>>(bsum, boff, SB);
    scan_final_kernel<<<SB, 256, 0, stream>>>(deg, boff, row_ptr, fill_pos, inv, N, E);
    fill_kernel<<<(E + 255) / 256, 256, 0, stream>>>(ei, E, fill_pos, colv);

    dim3 gg((N + 127) / 128, 4);
    // embed: h = x @ W_embed + b_embed
    gemm_kernel<false><<<gg, 256, 0, stream>>>(x, W_embed, b_embed, h, N, 118);
    for (int l = 0; l < 4; l++) {
        gemm_kernel<true><<<gg, 256, 0, stream>>>(h, W1 + (size_t)l * CH * CH,
                                                  b1 + (size_t)l * CH, t, N, CH);
        agg_kernel<<<(N + 3) / 4, 256, 0, stream>>>(t, row_ptr, colv, inv, agg, N);
        gemm_kernel<true><<<gg, 256, 0, stream>>>(agg, W2 + (size_t)l * CH * CH,
                                                  b2 + (size_t)l * CH, h, N, CH);
    }
    mean_kernel<<<(N + 3) / 4, 256, 0, stream>>>(h, out, N);
}

// Round 4
// 491.670 us; speedup vs baseline: 1.6216x; 1.4190x over previous
//
#include <hip/hip_runtime.h>
#include <math.h>

#define CH 256

typedef _Float16 half8 __attribute__((ext_vector_type(8)));
typedef float f32x4 __attribute__((ext_vector_type(4)));

__device__ __forceinline__ float gelu_exact(float v) {
    return 0.5f * v * (1.0f + erff(v * 0.70710678118654752f));
}

// ---------- W pre-split: W[k][n] fp32 -> WThi/WTlo[n][k] fp16 (transposed) ----
// 8 matrices (W1[0..3], W2[0..3]). Coalesced reads over n; 16B packed writes.
__global__ void wsplit_kernel(const float* __restrict__ W1, const float* __restrict__ W2,
                              _Float16* __restrict__ WThi, _Float16* __restrict__ WTlo) {
    int idx = blockIdx.x * blockDim.x + threadIdx.x;  // 8*256*32 = 65536 threads
    int n   = idx & 255;
    int kg  = (idx >> 8) & 31;      // k-group of 8
    int mat = idx >> 13;            // 0..7
    const float* W = (mat < 4) ? (W1 + (size_t)mat * 65536)
                               : (W2 + (size_t)(mat - 4) * 65536);
    _Float16 hi[8], lo[8];
#pragma unroll
    for (int j = 0; j < 8; j++) {
        float v = W[(size_t)(kg * 8 + j) * CH + n];
        _Float16 h = (_Float16)v;
        hi[j] = h;
        lo[j] = (_Float16)(v - (float)h);
    }
    size_t off = (size_t)mat * 65536 + (size_t)n * 256 + kg * 8;
    *(half8*)(WThi + off) = *(half8*)&hi[0];
    *(half8*)(WTlo + off) = *(half8*)&lo[0];
}

// ---------- fp16-split 3-pass MFMA GEMM: out = gelu(A @ W + bias), K=256 ----
// Tile 128x64, BK=32, 256 thr (4 waves 2x2, wave-tile 64x32, 16x16x32 frags).
// LDS 30KB/block. Strides padded to 40 f16 (80B): bank period 8 -> 2-way (free).
__global__ __launch_bounds__(256, 4) void mgemm_kernel(
    const float* __restrict__ A,           // [M][256] fp32
    const _Float16* __restrict__ Bhi_g,    // [256 n][256 k] fp16 hi (transposed)
    const _Float16* __restrict__ Blo_g,    // [256 n][256 k] fp16 lo
    const float* __restrict__ bias,        // [256]
    float* __restrict__ out,               // [M][256] fp32
    int M)
{
    __shared__ _Float16 Ah[128][40], Al[128][40], Bh[64][40], Bl[64][40];

    int tid  = threadIdx.x;
    int lane = tid & 63;
    int wave = tid >> 6;
    int wr = wave >> 1;            // 0..1 : 64-row block
    int wc = wave & 1;             // 0..1 : 32-col block
    int m0 = blockIdx.x * 128;
    int n0 = blockIdx.y * 64;

    f32x4 acc[4][2];
#pragma unroll
    for (int i = 0; i < 4; i++)
#pragma unroll
        for (int j = 0; j < 2; j++) acc[i][j] = (f32x4){0.f, 0.f, 0.f, 0.f};

    // A staging: one (row, 16-k chunk) per thread per k-tile
    const int s_row  = tid >> 1;
    const int s_ch   = (tid & 1) * 16;
    const int s_grow = min(m0 + s_row, M - 1);
    // B staging: waves 0-1 stage hi, waves 2-3 stage lo
    const int bcol = (tid & 127) >> 1;
    const int bch  = (tid & 1) * 16;

    for (int kt = 0; kt < 8; kt++) {
        int k0 = kt * 32;
        // ---- stage A (fp32 -> hi/lo fp16) ----
        {
            const float* src = A + (size_t)s_grow * CH + k0 + s_ch;
            float f[16];
            *(float4*)&f[0]  = ((const float4*)src)[0];
            *(float4*)&f[4]  = ((const float4*)src)[1];
            *(float4*)&f[8]  = ((const float4*)src)[2];
            *(float4*)&f[12] = ((const float4*)src)[3];
            _Float16 hi[16], lo[16];
#pragma unroll
            for (int j = 0; j < 16; j++) {
                _Float16 hh = (_Float16)f[j];
                hi[j] = hh;
                lo[j] = (_Float16)(f[j] - (float)hh);
            }
            *(half8*)&Ah[s_row][s_ch]     = *(half8*)&hi[0];
            *(half8*)&Ah[s_row][s_ch + 8] = *(half8*)&hi[8];
            *(half8*)&Al[s_row][s_ch]     = *(half8*)&lo[0];
            *(half8*)&Al[s_row][s_ch + 8] = *(half8*)&lo[8];
        }
        // ---- stage B (fp16 copy) ----
        {
            const _Float16* bs = ((tid < 128) ? Bhi_g : Blo_g)
                                 + (size_t)(n0 + bcol) * 256 + k0 + bch;
            half8 u0 = ((const half8*)bs)[0];
            half8 u1 = ((const half8*)bs)[1];
            _Float16 (*dst)[40] = (tid < 128) ? Bh : Bl;
            *(half8*)&dst[bcol][bch]     = u0;
            *(half8*)&dst[bcol][bch + 8] = u1;
        }
        __syncthreads();

        // ---- fragments + 24 MFMA ----
        {
            int frow = lane & 15;
            int fk   = (lane >> 4) * 8;
            half8 ah[4], al[4], bh[2], bl[2];
#pragma unroll
            for (int rf = 0; rf < 4; rf++) {
                int r = wr * 64 + rf * 16 + frow;
                ah[rf] = *(const half8*)&Ah[r][fk];
                al[rf] = *(const half8*)&Al[r][fk];
            }
#pragma unroll
            for (int cf = 0; cf < 2; cf++) {
                int c = wc * 32 + cf * 16 + frow;
                bh[cf] = *(const half8*)&Bh[c][fk];
                bl[cf] = *(const half8*)&Bl[c][fk];
            }
#pragma unroll
            for (int rf = 0; rf < 4; rf++)
#pragma unroll
                for (int cf = 0; cf < 2; cf++) {
                    acc[rf][cf] = __builtin_amdgcn_mfma_f32_16x16x32_f16(ah[rf], bh[cf], acc[rf][cf], 0, 0, 0);
                    acc[rf][cf] = __builtin_amdgcn_mfma_f32_16x16x32_f16(ah[rf], bl[cf], acc[rf][cf], 0, 0, 0);
                    acc[rf][cf] = __builtin_amdgcn_mfma_f32_16x16x32_f16(al[rf], bh[cf], acc[rf][cf], 0, 0, 0);
                }
        }
        __syncthreads();
    }

    // ---- epilogue: bias + exact GELU, C layout col=lane&15, row=(lane>>4)*4+q ----
    int ccol = lane & 15;
    int crow = (lane >> 4) * 4;
#pragma unroll
    for (int cf = 0; cf < 2; cf++) {
        int gcol = n0 + wc * 32 + cf * 16 + ccol;
        float bb = bias[gcol];
#pragma unroll
        for (int rf = 0; rf < 4; rf++) {
#pragma unroll
            for (int q = 0; q < 4; q++) {
                int grow = m0 + wr * 64 + rf * 16 + crow + q;
                if (grow < M)
                    out[(size_t)grow * CH + gcol] = gelu_exact(acc[rf][cf][q] + bb);
            }
        }
    }
}

// ---------------- fp32 VALU GEMM (embed only, K=118) ----------------
template<bool DOGELU>
__global__ __launch_bounds__(256) void gemm_kernel(const float* __restrict__ A,
                                                   const float* __restrict__ W,
                                                   const float* __restrict__ bias,
                                                   float* __restrict__ out,
                                                   int M, int K)
{
    const int BM = 128, BN = 64, BK = 64;
    __shared__ float As[BK][BM + 4];
    __shared__ float Bs[BK][BN + 4];

    int tid = threadIdx.x;
    int m0 = blockIdx.x * BM;
    int n0 = blockIdx.y * BN;
    int ty = tid >> 4;
    int tx = tid & 15;

    float acc[8][4];
#pragma unroll
    for (int i = 0; i < 8; i++)
#pragma unroll
        for (int j = 0; j < 4; j++) acc[i][j] = 0.f;

    const int s_arow = tid >> 2;
    const int s_akq  = tid & 3;
    const int s_bk   = tid >> 4;
    const int s_bc   = (tid & 15) * 4;
    const bool kalign = ((K & 3) == 0);

    for (int k0 = 0; k0 < K; k0 += BK) {
        const bool fullk = kalign && (k0 + BK <= K);
#pragma unroll
        for (int it = 0; it < 2; it++) {
            int row = it * 64 + s_arow;
            int grow = min(m0 + row, M - 1);
            const float* src = A + (size_t)grow * K;
            if (fullk) {
                int kb = k0 + s_akq * 16;
                float4 v0 = *(const float4*)(src + kb);
                float4 v1 = *(const float4*)(src + kb + 4);
                float4 v2 = *(const float4*)(src + kb + 8);
                float4 v3 = *(const float4*)(src + kb + 12);
                int kr = s_akq * 16;
                As[kr +  0][row] = v0.x; As[kr +  1][row] = v0.y;
                As[kr +  2][row] = v0.z; As[kr +  3][row] = v0.w;
                As[kr +  4][row] = v1.x; As[kr +  5][row] = v1.y;
                As[kr +  6][row] = v1.z; As[kr +  7][row] = v1.w;
                As[kr +  8][row] = v2.x; As[kr +  9][row] = v2.y;
                As[kr + 10][row] = v2.z; As[kr + 11][row] = v2.w;
                As[kr + 12][row] = v3.x; As[kr + 13][row] = v3.y;
                As[kr + 14][row] = v3.z; As[kr + 15][row] = v3.w;
            } else {
#pragma unroll
                for (int q = 0; q < 16; q++) {
                    int k = k0 + s_akq * 16 + q;
                    As[s_akq * 16 + q][row] = (k < K) ? src[min(k, K - 1)] : 0.f;
                }
            }
        }
#pragma unroll
        for (int it = 0; it < 4; it++) {
            int kr = it * 16 + s_bk;
            int gk = k0 + kr;
            float4 v = {0.f, 0.f, 0.f, 0.f};
            if (gk < K) v = *(const float4*)(W + (size_t)gk * CH + n0 + s_bc);
            *(float4*)&Bs[kr][s_bc] = v;
        }
        __syncthreads();

#pragma unroll 16
        for (int kk = 0; kk < BK; kk++) {
            float a[8], b[4];
            *(float4*)&a[0] = *(const float4*)&As[kk][ty * 8];
            *(float4*)&a[4] = *(const float4*)&As[kk][ty * 8 + 4];
            *(float4*)&b[0] = *(const float4*)&Bs[kk][tx * 4];
#pragma unroll
            for (int i = 0; i < 8; i++)
#pragma unroll
                for (int j = 0; j < 4; j++)
                    acc[i][j] = fmaf(a[i], b[j], acc[i][j]);
        }
        __syncthreads();
    }

    float b4[4];
    *(float4*)&b4[0] = *(const float4*)(bias + n0 + tx * 4);
#pragma unroll
    for (int i = 0; i < 8; i++) {
        int row = m0 + ty * 8 + i;
        if (row < M) {
            float o[4];
#pragma unroll
            for (int j = 0; j < 4; j++) {
                float v = acc[i][j] + b4[j];
                o[j] = DOGELU ? gelu_exact(v) : v;
            }
            *(float4*)(out + (size_t)row * CH + n0 + tx * 4) = *(float4*)&o[0];
        }
    }
}

// ---------------- CSR build ----------------
__global__ void zero_int_kernel(int* p, int n) {
    int i = blockIdx.x * blockDim.x + threadIdx.x;
    if (i < n) p[i] = 0;
}

__global__ void degree_kernel(const int* __restrict__ ei, int E, int* deg) {
    int e = blockIdx.x * blockDim.x + threadIdx.x;
    if (e < E) atomicAdd(&deg[ei[E + e]], 1);
}

__global__ void scan_part_kernel(const int* __restrict__ deg, int* bsum, int N) {
    int t = threadIdx.x;
    int base = blockIdx.x * 1024 + t * 4;
    int4 v = {0, 0, 0, 0};
    if (base + 3 < N) v = *(const int4*)(deg + base);
    else {
        if (base + 0 < N) v.x = deg[base + 0];
        if (base + 1 < N) v.y = deg[base + 1];
        if (base + 2 < N) v.z = deg[base + 2];
        if (base + 3 < N) v.w = deg[base + 3];
    }
    __shared__ int sh[256];
    sh[t] = v.x + v.y + v.z + v.w;
    __syncthreads();
    for (int off = 128; off; off >>= 1) {
        if (t < off) sh[t] += sh[t + off];
        __syncthreads();
    }
    if (t == 0) bsum[blockIdx.x] = sh[0];
}

__global__ void scan_top_kernel(const int* __restrict__ bsum, int* boff, int B) {
    __shared__ int sh[256];
    int t = threadIdx.x;
    int own = (t < B) ? bsum[t] : 0;
    sh[t] = own;
    __syncthreads();
    for (int off = 1; off < 256; off <<= 1) {
        int v = (t >= off) ? sh[t - off] : 0;
        __syncthreads();
        sh[t] += v;
        __syncthreads();
    }
    if (t < B) boff[t] = sh[t] - own;
}

__global__ void scan_final_kernel(const int* __restrict__ deg, const int* __restrict__ boff,
                                  int* row_ptr, int* fill_pos, float* inv, int N, int E) {
    int t = threadIdx.x;
    int base = blockIdx.x * 1024 + t * 4;
    int4 v = {0, 0, 0, 0};
    if (base + 3 < N) v = *(const int4*)(deg + base);
    else {
        if (base + 0 < N) v.x = deg[base + 0];
        if (base + 1 < N) v.y = deg[base + 1];
        if (base + 2 < N) v.z = deg[base + 2];
        if (base + 3 < N) v.w = deg[base + 3];
    }
    int own = v.x + v.y + v.z + v.w;
    __shared__ int sh[256];
    sh[t] = own;
    __syncthreads();
    for (int off = 1; off < 256; off <<= 1) {
        int s = (t >= off) ? sh[t - off] : 0;
        __syncthreads();
        sh[t] += s;
        __syncthreads();
    }
    int run = boff[blockIdx.x] + (sh[t] - own);
    int4 rp;
    rp.x = run;
    rp.y = run + v.x;
    rp.z = rp.y + v.y;
    rp.w = rp.z + v.z;
    if (base + 3 < N) {
        *(int4*)(row_ptr + base) = rp;
        *(int4*)(fill_pos + base) = rp;
        float4 iv;
        iv.x = 1.0f / fmaxf((float)v.x, 1.0f);
        iv.y = 1.0f / fmaxf((float)v.y, 1.0f);
        iv.z = 1.0f / fmaxf((float)v.z, 1.0f);
        iv.w = 1.0f / fmaxf((float)v.w, 1.0f);
        *(float4*)(inv + base) = iv;
    } else {
        int rr[4] = {rp.x, rp.y, rp.z, rp.w};
        int dd[4] = {v.x, v.y, v.z, v.w};
        for (int q = 0; q < 4; q++) {
            if (base + q < N) {
                row_ptr[base + q] = rr[q];
                fill_pos[base + q] = rr[q];
                inv[base + q] = 1.0f / fmaxf((float)dd[q], 1.0f);
            }
        }
    }
    if (blockIdx.x == 0 && t == 0) row_ptr[N] = E;
}

__global__ void fill_kernel(const int* __restrict__ ei, int E, int* fill_pos, int* colv) {
    int e = blockIdx.x * blockDim.x + threadIdx.x;
    if (e < E) {
        int p = atomicAdd(&fill_pos[ei[E + e]], 1);
        colv[p] = ei[e];
    }
}

// ---------------- aggregation + mean ----------------
__global__ void agg_kernel(const float* __restrict__ t, const int* __restrict__ row_ptr,
                           const int* __restrict__ colv, const float* __restrict__ inv,
                           float* __restrict__ agg, int N) {
    int n = blockIdx.x * 4 + (threadIdx.x >> 6);
    if (n >= N) return;
    int lane = threadIdx.x & 63;
    int s = row_ptr[n], e = row_ptr[n + 1];
    float a0 = 0.f, a1 = 0.f, a2 = 0.f, a3 = 0.f;
    for (int j = s; j < e; j++) {
        const float* p = t + (size_t)colv[j] * CH + lane * 4;
        float4 v = *(const float4*)p;
        a0 += v.x; a1 += v.y; a2 += v.z; a3 += v.w;
    }
    float sc = inv[n];
    float o[4] = {a0 * sc, a1 * sc, a2 * sc, a3 * sc};
    *(float4*)(agg + (size_t)n * CH + lane * 4) = *(float4*)&o[0];
}

__global__ void mean_kernel(const float* __restrict__ h, float* __restrict__ out, int N) {
    int n = blockIdx.x * 4 + (threadIdx.x >> 6);
    if (n >= N) return;
    int lane = threadIdx.x & 63;
    float4 v = *(const float4*)(h + (size_t)n * CH + lane * 4);
    float s = v.x + v.y + v.z + v.w;
#pragma unroll
    for (int off = 32; off; off >>= 1) s += __shfl_down(s, off, 64);
    if (lane == 0) out[n] = s * (1.0f / 256.0f);
}

extern "C" void kernel_launch(void* const* d_in, const int* in_sizes, int n_in,
                              void* d_out, int out_size, void* d_ws, size_t ws_size,
                              hipStream_t stream) {
    const float* x       = (const float*)d_in[0];
    const int*   ei      = (const int*)d_in[1];
    const float* W_embed = (const float*)d_in[2];
    const float* b_embed = (const float*)d_in[3];
    const float* W1      = (const float*)d_in[4];
    const float* b1      = (const float*)d_in[5];
    const float* W2      = (const float*)d_in[6];
    const float* b2      = (const float*)d_in[7];
    float* out = (float*)d_out;

    int N = in_sizes[0] / 118;
    int E = in_sizes[1] / 2;
    int SB = (N + 1023) / 1024;

    // workspace layout
    float*     h        = (float*)d_ws;                  // N*256
    float*     t        = h + (size_t)N * CH;            // N*256
    float*     agg      = t + (size_t)N * CH;            // N*256
    _Float16*  WThi     = (_Float16*)(agg + (size_t)N * CH);  // 8*65536 f16
    _Float16*  WTlo     = WThi + 8 * 65536;              // 8*65536 f16
    float*     inv      = (float*)(WTlo + 8 * 65536);    // N
    int*       deg      = (int*)(inv + N);               // N
    int*       row_ptr  = deg + N;                       // N+1
    int*       fill_pos = row_ptr + (N + 1);             // N
    int*       colv     = fill_pos + N;                  // E
    int*       bsum     = colv + E;                      // SB
    int*       boff     = bsum + 256;                    // SB

    // CSR build + weight split (once per launch, deterministic)
    zero_int_kernel<<<(N + 255) / 256, 256, 0, stream>>>(deg, N);
    degree_kernel<<<(E + 255) / 256, 256, 0, stream>>>(ei, E, deg);
    scan_part_kernel<<<SB, 256, 0, stream>>>(deg, bsum, N);
    scan_top_kernel<<<1, 256, 0, stream>>>(bsum, boff, SB);
    scan_final_kernel<<<SB, 256, 0, stream>>>(deg, boff, row_ptr, fill_pos, inv, N, E);
    fill_kernel<<<(E + 255) / 256, 256, 0, stream>>>(ei, E, fill_pos, colv);
    wsplit_kernel<<<256, 256, 0, stream>>>(W1, W2, WThi, WTlo);

    // embed: h = x @ W_embed + b_embed (fp32 VALU path, K=118)
    dim3 gg((N + 127) / 128, 4);
    gemm_kernel<false><<<gg, 256, 0, stream>>>(x, W_embed, b_embed, h, N, 118);

    dim3 mg((N + 127) / 128, 4);
    for (int l = 0; l < 4; l++) {
        mgemm_kernel<<<mg, 256, 0, stream>>>(h, WThi + (size_t)l * 65536,
                                             WTlo + (size_t)l * 65536,
                                             b1 + (size_t)l * CH, t, N);
        agg_kernel<<<(N + 3) / 4, 256, 0, stream>>>(t, row_ptr, colv, inv, agg, N);
        mgemm_kernel<<<mg, 256, 0, stream>>>(agg, WThi + (size_t)(4 + l) * 65536,
                                             WTlo + (size_t)(4 + l) * 65536,
                                             b2 + (size_t)l * CH, h, N);
    }
    mean_kernel<<<(N + 3) / 4, 256, 0, stream>>>(h, out, N);
}

// Round 5
// 468.622 us; speedup vs baseline: 1.7013x; 1.0492x over previous
//
#include <hip/hip_runtime.h>
#include <math.h>

#define CH 256

typedef _Float16 half8 __attribute__((ext_vector_type(8)));
typedef float f32x4 __attribute__((ext_vector_type(4)));

__device__ __forceinline__ float gelu_exact(float v) {
    return 0.5f * v * (1.0f + erff(v * 0.70710678118654752f));
}

// ---------- W pre-split: W[k][n] fp32 -> WThi/WTlo[n][k] fp16 (transposed) ----
__global__ void wsplit_kernel(const float* __restrict__ W1, const float* __restrict__ W2,
                              _Float16* __restrict__ WThi, _Float16* __restrict__ WTlo) {
    int idx = blockIdx.x * blockDim.x + threadIdx.x;  // 65536 threads
    int n   = idx & 255;
    int kg  = (idx >> 8) & 31;
    int mat = idx >> 13;
    const float* W = (mat < 4) ? (W1 + (size_t)mat * 65536)
                               : (W2 + (size_t)(mat - 4) * 65536);
    _Float16 hi[8], lo[8];
#pragma unroll
    for (int j = 0; j < 8; j++) {
        float v = W[(size_t)(kg * 8 + j) * CH + n];
        _Float16 h = (_Float16)v;
        hi[j] = h;
        lo[j] = (_Float16)(v - (float)h);
    }
    size_t off = (size_t)mat * 65536 + (size_t)n * 256 + kg * 8;
    *(half8*)(WThi + off) = *(half8*)&hi[0];
    *(half8*)(WTlo + off) = *(half8*)&lo[0];
}

// ---------- fp16-split 3-pass MFMA GEMM: out = gelu(A @ W + bias), K=256 ----
__global__ __launch_bounds__(256, 4) void mgemm_kernel(
    const float* __restrict__ A,
    const _Float16* __restrict__ Bhi_g,
    const _Float16* __restrict__ Blo_g,
    const float* __restrict__ bias,
    float* __restrict__ out,
    int M)
{
    __shared__ _Float16 Ah[128][40], Al[128][40], Bh[64][40], Bl[64][40];

    int tid  = threadIdx.x;
    int lane = tid & 63;
    int wave = tid >> 6;
    int wr = wave >> 1;
    int wc = wave & 1;
    int m0 = blockIdx.x * 128;
    int n0 = blockIdx.y * 64;

    f32x4 acc[4][2];
#pragma unroll
    for (int i = 0; i < 4; i++)
#pragma unroll
        for (int j = 0; j < 2; j++) acc[i][j] = (f32x4){0.f, 0.f, 0.f, 0.f};

    const int s_row  = tid >> 1;
    const int s_ch   = (tid & 1) * 16;
    const int s_grow = min(m0 + s_row, M - 1);
    const int bcol = (tid & 127) >> 1;
    const int bch  = (tid & 1) * 16;

    for (int kt = 0; kt < 8; kt++) {
        int k0 = kt * 32;
        {
            const float* src = A + (size_t)s_grow * CH + k0 + s_ch;
            float f[16];
            *(float4*)&f[0]  = ((const float4*)src)[0];
            *(float4*)&f[4]  = ((const float4*)src)[1];
            *(float4*)&f[8]  = ((const float4*)src)[2];
            *(float4*)&f[12] = ((const float4*)src)[3];
            _Float16 hi[16], lo[16];
#pragma unroll
            for (int j = 0; j < 16; j++) {
                _Float16 hh = (_Float16)f[j];
                hi[j] = hh;
                lo[j] = (_Float16)(f[j] - (float)hh);
            }
            *(half8*)&Ah[s_row][s_ch]     = *(half8*)&hi[0];
            *(half8*)&Ah[s_row][s_ch + 8] = *(half8*)&hi[8];
            *(half8*)&Al[s_row][s_ch]     = *(half8*)&lo[0];
            *(half8*)&Al[s_row][s_ch + 8] = *(half8*)&lo[8];
        }
        {
            const _Float16* bs = ((tid < 128) ? Bhi_g : Blo_g)
                                 + (size_t)(n0 + bcol) * 256 + k0 + bch;
            half8 u0 = ((const half8*)bs)[0];
            half8 u1 = ((const half8*)bs)[1];
            _Float16 (*dst)[40] = (tid < 128) ? Bh : Bl;
            *(half8*)&dst[bcol][bch]     = u0;
            *(half8*)&dst[bcol][bch + 8] = u1;
        }
        __syncthreads();

        {
            int frow = lane & 15;
            int fk   = (lane >> 4) * 8;
            half8 ah[4], al[4], bh[2], bl[2];
#pragma unroll
            for (int rf = 0; rf < 4; rf++) {
                int r = wr * 64 + rf * 16 + frow;
                ah[rf] = *(const half8*)&Ah[r][fk];
                al[rf] = *(const half8*)&Al[r][fk];
            }
#pragma unroll
            for (int cf = 0; cf < 2; cf++) {
                int c = wc * 32 + cf * 16 + frow;
                bh[cf] = *(const half8*)&Bh[c][fk];
                bl[cf] = *(const half8*)&Bl[c][fk];
            }
#pragma unroll
            for (int rf = 0; rf < 4; rf++)
#pragma unroll
                for (int cf = 0; cf < 2; cf++) {
                    acc[rf][cf] = __builtin_amdgcn_mfma_f32_16x16x32_f16(ah[rf], bh[cf], acc[rf][cf], 0, 0, 0);
                    acc[rf][cf] = __builtin_amdgcn_mfma_f32_16x16x32_f16(ah[rf], bl[cf], acc[rf][cf], 0, 0, 0);
                    acc[rf][cf] = __builtin_amdgcn_mfma_f32_16x16x32_f16(al[rf], bh[cf], acc[rf][cf], 0, 0, 0);
                }
        }
        __syncthreads();
    }

    int ccol = lane & 15;
    int crow = (lane >> 4) * 4;
#pragma unroll
    for (int cf = 0; cf < 2; cf++) {
        int gcol = n0 + wc * 32 + cf * 16 + ccol;
        float bb = bias[gcol];
#pragma unroll
        for (int rf = 0; rf < 4; rf++) {
#pragma unroll
            for (int q = 0; q < 4; q++) {
                int grow = m0 + wr * 64 + rf * 16 + crow + q;
                if (grow < M)
                    out[(size_t)grow * CH + gcol] = gelu_exact(acc[rf][cf][q] + bb);
            }
        }
    }
}

// ---------------- fp32 VALU GEMM (embed only, K=118) ----------------
template<bool DOGELU>
__global__ __launch_bounds__(256) void gemm_kernel(const float* __restrict__ A,
                                                   const float* __restrict__ W,
                                                   const float* __restrict__ bias,
                                                   float* __restrict__ out,
                                                   int M, int K)
{
    const int BM = 128, BN = 64, BK = 64;
    __shared__ float As[BK][BM + 4];
    __shared__ float Bs[BK][BN + 4];

    int tid = threadIdx.x;
    int m0 = blockIdx.x * BM;
    int n0 = blockIdx.y * BN;
    int ty = tid >> 4;
    int tx = tid & 15;

    float acc[8][4];
#pragma unroll
    for (int i = 0; i < 8; i++)
#pragma unroll
        for (int j = 0; j < 4; j++) acc[i][j] = 0.f;

    const int s_arow = tid >> 2;
    const int s_akq  = tid & 3;
    const int s_bk   = tid >> 4;
    const int s_bc   = (tid & 15) * 4;
    const bool kalign = ((K & 3) == 0);

    for (int k0 = 0; k0 < K; k0 += BK) {
        const bool fullk = kalign && (k0 + BK <= K);
#pragma unroll
        for (int it = 0; it < 2; it++) {
            int row = it * 64 + s_arow;
            int grow = min(m0 + row, M - 1);
            const float* src = A + (size_t)grow * K;
            if (fullk) {
                int kb = k0 + s_akq * 16;
                float4 v0 = *(const float4*)(src + kb);
                float4 v1 = *(const float4*)(src + kb + 4);
                float4 v2 = *(const float4*)(src + kb + 8);
                float4 v3 = *(const float4*)(src + kb + 12);
                int kr = s_akq * 16;
                As[kr +  0][row] = v0.x; As[kr +  1][row] = v0.y;
                As[kr +  2][row] = v0.z; As[kr +  3][row] = v0.w;
                As[kr +  4][row] = v1.x; As[kr +  5][row] = v1.y;
                As[kr +  6][row] = v1.z; As[kr +  7][row] = v1.w;
                As[kr +  8][row] = v2.x; As[kr +  9][row] = v2.y;
                As[kr + 10][row] = v2.z; As[kr + 11][row] = v2.w;
                As[kr + 12][row] = v3.x; As[kr + 13][row] = v3.y;
                As[kr + 14][row] = v3.z; As[kr + 15][row] = v3.w;
            } else {
#pragma unroll
                for (int q = 0; q < 16; q++) {
                    int k = k0 + s_akq * 16 + q;
                    As[s_akq * 16 + q][row] = (k < K) ? src[min(k, K - 1)] : 0.f;
                }
            }
        }
#pragma unroll
        for (int it = 0; it < 4; it++) {
            int kr = it * 16 + s_bk;
            int gk = k0 + kr;
            float4 v = {0.f, 0.f, 0.f, 0.f};
            if (gk < K) v = *(const float4*)(W + (size_t)gk * CH + n0 + s_bc);
            *(float4*)&Bs[kr][s_bc] = v;
        }
        __syncthreads();

#pragma unroll 16
        for (int kk = 0; kk < BK; kk++) {
            float a[8], b[4];
            *(float4*)&a[0] = *(const float4*)&As[kk][ty * 8];
            *(float4*)&a[4] = *(const float4*)&As[kk][ty * 8 + 4];
            *(float4*)&b[0] = *(const float4*)&Bs[kk][tx * 4];
#pragma unroll
            for (int i = 0; i < 8; i++)
#pragma unroll
                for (int j = 0; j < 4; j++)
                    acc[i][j] = fmaf(a[i], b[j], acc[i][j]);
        }
        __syncthreads();
    }

    float b4[4];
    *(float4*)&b4[0] = *(const float4*)(bias + n0 + tx * 4);
#pragma unroll
    for (int i = 0; i < 8; i++) {
        int row = m0 + ty * 8 + i;
        if (row < M) {
            float o[4];
#pragma unroll
            for (int j = 0; j < 4; j++) {
                float v = acc[i][j] + b4[j];
                o[j] = DOGELU ? gelu_exact(v) : v;
            }
            *(float4*)(out + (size_t)row * CH + n0 + tx * 4) = *(float4*)&o[0];
        }
    }
}

// ---------------- CSR build ----------------
__global__ void zero_int_kernel(int* p, int n) {
    int i = blockIdx.x * blockDim.x + threadIdx.x;
    if (i < n) p[i] = 0;
}

__global__ void degree_kernel(const int* __restrict__ ei, int E, int* deg) {
    int e = blockIdx.x * blockDim.x + threadIdx.x;
    if (e < E) atomicAdd(&deg[ei[E + e]], 1);
}

__global__ void scan_part_kernel(const int* __restrict__ deg, int* bsum, int N) {
    int t = threadIdx.x;
    int base = blockIdx.x * 1024 + t * 4;
    int4 v = {0, 0, 0, 0};
    if (base + 3 < N) v = *(const int4*)(deg + base);
    else {
        if (base + 0 < N) v.x = deg[base + 0];
        if (base + 1 < N) v.y = deg[base + 1];
        if (base + 2 < N) v.z = deg[base + 2];
        if (base + 3 < N) v.w = deg[base + 3];
    }
    __shared__ int sh[256];
    sh[t] = v.x + v.y + v.z + v.w;
    __syncthreads();
    for (int off = 128; off; off >>= 1) {
        if (t < off) sh[t] += sh[t + off];
        __syncthreads();
    }
    if (t == 0) bsum[blockIdx.x] = sh[0];
}

__global__ void scan_top_kernel(const int* __restrict__ bsum, int* boff, int B) {
    __shared__ int sh[256];
    int t = threadIdx.x;
    int own = (t < B) ? bsum[t] : 0;
    sh[t] = own;
    __syncthreads();
    for (int off = 1; off < 256; off <<= 1) {
        int v = (t >= off) ? sh[t - off] : 0;
        __syncthreads();
        sh[t] += v;
        __syncthreads();
    }
    if (t < B) boff[t] = sh[t] - own;
}

__global__ void scan_final_kernel(const int* __restrict__ deg, const int* __restrict__ boff,
                                  int* row_ptr, int* fill_pos, float* inv, int N, int E) {
    int t = threadIdx.x;
    int base = blockIdx.x * 1024 + t * 4;
    int4 v = {0, 0, 0, 0};
    if (base + 3 < N) v = *(const int4*)(deg + base);
    else {
        if (base + 0 < N) v.x = deg[base + 0];
        if (base + 1 < N) v.y = deg[base + 1];
        if (base + 2 < N) v.z = deg[base + 2];
        if (base + 3 < N) v.w = deg[base + 3];
    }
    int own = v.x + v.y + v.z + v.w;
    __shared__ int sh[256];
    sh[t] = own;
    __syncthreads();
    for (int off = 1; off < 256; off <<= 1) {
        int s = (t >= off) ? sh[t - off] : 0;
        __syncthreads();
        sh[t] += s;
        __syncthreads();
    }
    int run = boff[blockIdx.x] + (sh[t] - own);
    int4 rp;
    rp.x = run;
    rp.y = run + v.x;
    rp.z = rp.y + v.y;
    rp.w = rp.z + v.z;
    if (base + 3 < N) {
        *(int4*)(row_ptr + base) = rp;
        *(int4*)(fill_pos + base) = rp;
        float4 iv;
        iv.x = 1.0f / fmaxf((float)v.x, 1.0f);
        iv.y = 1.0f / fmaxf((float)v.y, 1.0f);
        iv.z = 1.0f / fmaxf((float)v.z, 1.0f);
        iv.w = 1.0f / fmaxf((float)v.w, 1.0f);
        *(float4*)(inv + base) = iv;
    } else {
        int rr[4] = {rp.x, rp.y, rp.z, rp.w};
        int dd[4] = {v.x, v.y, v.z, v.w};
        for (int q = 0; q < 4; q++) {
            if (base + q < N) {
                row_ptr[base + q] = rr[q];
                fill_pos[base + q] = rr[q];
                inv[base + q] = 1.0f / fmaxf((float)dd[q], 1.0f);
            }
        }
    }
    if (blockIdx.x == 0 && t == 0) row_ptr[N] = E;
}

__global__ void fill_kernel(const int* __restrict__ ei, int E, int* fill_pos, int* colv) {
    int e = blockIdx.x * blockDim.x + threadIdx.x;
    if (e < E) {
        int p = atomicAdd(&fill_pos[ei[E + e]], 1);
        colv[p] = ei[e];
    }
}

// ---------------- aggregation: unroll-by-4 for 4x memory-level parallelism ----
__global__ void agg_kernel(const float* __restrict__ t, const int* __restrict__ row_ptr,
                           const int* __restrict__ colv, const float* __restrict__ inv,
                           float* __restrict__ agg, int N) {
    int n = blockIdx.x * 4 + (threadIdx.x >> 6);
    if (n >= N) return;
    int lane = threadIdx.x & 63;
    int s = row_ptr[n], e = row_ptr[n + 1];
    size_t loff = (size_t)lane * 4;

    f32x4 a0 = {0.f, 0.f, 0.f, 0.f}, a1 = a0, a2 = a0, a3 = a0;
    int j = s;
    for (; j + 4 <= e; j += 4) {
        // batch the 4 index loads, then 4 independent 1KB row gathers in flight
        int c0 = colv[j], c1 = colv[j + 1], c2 = colv[j + 2], c3 = colv[j + 3];
        const float4* p0 = (const float4*)(t + (size_t)c0 * CH + loff);
        const float4* p1 = (const float4*)(t + (size_t)c1 * CH + loff);
        const float4* p2 = (const float4*)(t + (size_t)c2 * CH + loff);
        const float4* p3 = (const float4*)(t + (size_t)c3 * CH + loff);
        float4 v0 = *p0; float4 v1 = *p1; float4 v2 = *p2; float4 v3 = *p3;
        a0 += (f32x4){v0.x, v0.y, v0.z, v0.w};
        a1 += (f32x4){v1.x, v1.y, v1.z, v1.w};
        a2 += (f32x4){v2.x, v2.y, v2.z, v2.w};
        a3 += (f32x4){v3.x, v3.y, v3.z, v3.w};
    }
    for (; j < e; j++) {
        float4 v = *(const float4*)(t + (size_t)colv[j] * CH + loff);
        a0 += (f32x4){v.x, v.y, v.z, v.w};
    }
    f32x4 tot = (a0 + a1) + (a2 + a3);
    float sc = inv[n];
    float o[4] = {tot[0] * sc, tot[1] * sc, tot[2] * sc, tot[3] * sc};
    *(float4*)(agg + (size_t)n * CH + loff) = *(float4*)&o[0];
}

__global__ void mean_kernel(const float* __restrict__ h, float* __restrict__ out, int N) {
    int n = blockIdx.x * 4 + (threadIdx.x >> 6);
    if (n >= N) return;
    int lane = threadIdx.x & 63;
    float4 v = *(const float4*)(h + (size_t)n * CH + lane * 4);
    float s = v.x + v.y + v.z + v.w;
#pragma unroll
    for (int off = 32; off; off >>= 1) s += __shfl_down(s, off, 64);
    if (lane == 0) out[n] = s * (1.0f / 256.0f);
}

extern "C" void kernel_launch(void* const* d_in, const int* in_sizes, int n_in,
                              void* d_out, int out_size, void* d_ws, size_t ws_size,
                              hipStream_t stream) {
    const float* x       = (const float*)d_in[0];
    const int*   ei      = (const int*)d_in[1];
    const float* W_embed = (const float*)d_in[2];
    const float* b_embed = (const float*)d_in[3];
    const float* W1      = (const float*)d_in[4];
    const float* b1      = (const float*)d_in[5];
    const float* W2      = (const float*)d_in[6];
    const float* b2      = (const float*)d_in[7];
    float* out = (float*)d_out;

    int N = in_sizes[0] / 118;
    int E = in_sizes[1] / 2;
    int SB = (N + 1023) / 1024;

    // workspace layout
    float*     h        = (float*)d_ws;
    float*     t        = h + (size_t)N * CH;
    float*     agg      = t + (size_t)N * CH;
    _Float16*  WThi     = (_Float16*)(agg + (size_t)N * CH);
    _Float16*  WTlo     = WThi + 8 * 65536;
    float*     inv      = (float*)(WTlo + 8 * 65536);
    int*       deg      = (int*)(inv + N);
    int*       row_ptr  = deg + N;
    int*       fill_pos = row_ptr + (N + 1);
    int*       colv     = fill_pos + N;
    int*       bsum     = colv + E;
    int*       boff     = bsum + 256;

    zero_int_kernel<<<(N + 255) / 256, 256, 0, stream>>>(deg, N);
    degree_kernel<<<(E + 255) / 256, 256, 0, stream>>>(ei, E, deg);
    scan_part_kernel<<<SB, 256, 0, stream>>>(deg, bsum, N);
    scan_top_kernel<<<1, 256, 0, stream>>>(bsum, boff, SB);
    scan_final_kernel<<<SB, 256, 0, stream>>>(deg, boff, row_ptr, fill_pos, inv, N, E);
    fill_kernel<<<(E + 255) / 256, 256, 0, stream>>>(ei, E, fill_pos, colv);
    wsplit_kernel<<<256, 256, 0, stream>>>(W1, W2, WThi, WTlo);

    dim3 gg((N + 127) / 128, 4);
    gemm_kernel<false><<<gg, 256, 0, stream>>>(x, W_embed, b_embed, h, N, 118);

    dim3 mg((N + 127) / 128, 4);
    for (int l = 0; l < 4; l++) {
        mgemm_kernel<<<mg, 256, 0, stream>>>(h, WThi + (size_t)l * 65536,
                                             WTlo + (size_t)l * 65536,
                                             b1 + (size_t)l * CH, t, N);
        agg_kernel<<<(N + 3) / 4, 256, 0, stream>>>(t, row_ptr, colv, inv, agg, N);
        mgemm_kernel<<<mg, 256, 0, stream>>>(agg, WThi + (size_t)(4 + l) * 65536,
                                             WTlo + (size_t)(4 + l) * 65536,
                                             b2 + (size_t)l * CH, h, N);
    }
    mean_kernel<<<(N + 3) / 4, 256, 0, stream>>>(h, out, N);
}